// Round 7
// baseline (236.125 us; speedup 1.0000x reference)
//
#include <hip/hip_runtime.h>
#include <stdint.h>

#define B_SZ   2048
#define IN_SZ  1024
#define OUT_SZ 1024
#define Q_SZ   16

typedef __attribute__((ext_vector_type(8))) short short8;   // 8 bf16 (4 VGPRs)
typedef __attribute__((ext_vector_type(4))) float floatx4;  // MFMA accumulator
typedef __attribute__((ext_vector_type(2))) unsigned short u16x2;

__device__ __forceinline__ unsigned short f32_to_bf16_rne(float f) {
    union { float f; uint32_t u; } v; v.f = f;
    uint32_t u = v.u;
    return (unsigned short)((u + 0x7FFFu + ((u >> 16) & 1u)) >> 16);
}

// packed 2x16-bit: out = (iv16==q16) ? xv16 : 0.  t=iv^qq; m=min(t,1)-1
// (0xFFFF iff t==0 since idx,q<16); return x & m.  Exact.
__device__ __forceinline__ uint32_t mask2(uint32_t xv, uint32_t iv, uint32_t qq) {
    union { uint32_t u; u16x2 v; } t, m;
    t.u = iv ^ qq;
    u16x2 one; one.x = 1; one.y = 1;
    m.v = __builtin_elementwise_min(t.v, one) - one;
    return xv & m.u;
}

// ---------------- prep: fragment-linear Wf ----------------
// Slab S = (zb*8+xb)*32 + ih*16 + q   (16 KB each; 2048 slabs = 32 MB)
// chunk c = (h*8+nt)*64 + lane, 16B:  element j of lane's B-frag =
//   bf16( W[(q*1024 + i)*1024 + o] ),  o = xb*128+nt*16+(lane&15),
//   i = zb*128 + ih*64 + h*32 + (lane>>4)*8 + j
__global__ void k_build_wf(const float* __restrict__ W, unsigned short* __restrict__ Wf) {
    const int S = blockIdx.x;
    const int q  = S & 15, ih = (S >> 4) & 1, xb = (S >> 5) & 7, zb = S >> 8;
    const int t = threadIdx.x;
    unsigned short* dst = Wf + (size_t)S * 8192;
#pragma unroll
    for (int it = 0; it < 4; ++it) {
        int c = it * 256 + t;
        int L = c & 63;
        int hnt = c >> 6;                      // h*8+nt
        int h = hnt >> 3, nt = hnt & 7;
        int o  = xb * 128 + nt * 16 + (L & 15);
        int i0 = zb * 128 + ih * 64 + h * 32 + (L >> 4) * 8;
        const float* src = W + ((size_t)(q * 1024 + i0)) * 1024 + o;
        unsigned short v[8];
#pragma unroll
        for (int j = 0; j < 8; ++j) v[j] = f32_to_bf16_rne(src[(size_t)j * 1024]);
        *(uint4*)(dst + (size_t)c * 8) = *(uint4*)v;
    }
}

// ---------------- fused GEMM, LDS-free ----------------
// Block: 128b x 128o x (i-window 128, all 16 q). Wave: 32b x 128o.
// B-frags: 16 coalesced 1KB global loads per step from frag-linear Wf
// (L1-shared by the 4 waves; bare s_barrier keeps them converged).
// A: raw x/idx -> registers, converted/packed twice per block; masked per q.
__global__ __launch_bounds__(256, 3) void k_gemm(const unsigned short* __restrict__ Wf,
                                                 const float* __restrict__ x,
                                                 const int* __restrict__ idx,
                                                 const float* __restrict__ bias,
                                                 float* __restrict__ out) {
    const int tid  = threadIdx.x;
    const int wave = tid >> 6, lane = tid & 63;

    // id = zb + 8*xb + 64*yb -> XCD (id%8) = zb; the 16 y-blocks sharing this
    // (xb,zb) Wf window (512 KB) land on one XCD for L2 reuse.
    const int id = blockIdx.x;
    const int zb = id & 7;
    const int xb = (id >> 3) & 7;
    const int yb = id >> 6;
    const int o0 = xb * 128, b0 = yb * 128, ibase = zb * 128;

    const char* slab0 = (const char*)Wf + ((size_t)(zb * 8 + xb) * 32) * 16384 + lane * 16;

    const int arow = b0 + wave * 32 + (lane & 15);
    const float* xg = x + (size_t)arow * IN_SZ + ibase + (lane >> 4) * 8;
    const int*   ig = idx + (size_t)arow * IN_SZ + ibase + (lane >> 4) * 8;

    floatx4 acc[16];
#pragma unroll
    for (int i = 0; i < 16; ++i) acc[i] = (floatx4){0.f, 0.f, 0.f, 0.f};

    uint4 xr[2][2], ir[2][2];

    for (int s = 0; s < 32; ++s) {
        if ((s & 15) == 0) {                   // new i-half: load+convert A regs
            int io = (s >> 4) * 64;
#pragma unroll
            for (int mt = 0; mt < 2; ++mt)
#pragma unroll
                for (int hh = 0; hh < 2; ++hh) {
                    const float* xp = xg + mt * 16 * IN_SZ + io + hh * 32;
                    const int*   ip = ig + mt * 16 * IN_SZ + io + hh * 32;
                    float a[8]; int b[8];
                    *(float4*)(a)     = *(const float4*)xp;
                    *(float4*)(a + 4) = *((const float4*)xp + 1);
                    *(int4*)(b)       = *(const int4*)ip;
                    *(int4*)(b + 4)   = *((const int4*)ip + 1);
                    unsigned short xv[8];
#pragma unroll
                    for (int j = 0; j < 8; ++j) xv[j] = f32_to_bf16_rne(a[j]);
                    xr[mt][hh] = *(uint4*)xv;
                    uint32_t iw[4];
#pragma unroll
                    for (int w = 0; w < 4; ++w)
                        iw[w] = ((uint32_t)b[2 * w] & 0xFFFFu) | ((uint32_t)b[2 * w + 1] << 16);
                    ir[mt][hh] = *(uint4*)iw;
                }
        }
        const uint32_t qq = (uint32_t)(s & 15) * 0x00010001u;
        const char* sl = slab0 + (size_t)s * 16384;
#pragma unroll
        for (int h = 0; h < 2; ++h) {
            short8 bF[8];
#pragma unroll
            for (int nt = 0; nt < 8; ++nt)
                bF[nt] = *(const short8*)(sl + (h * 8 + nt) * 1024);
            union { uint4 u; short8 s8; } aF[2];
#pragma unroll
            for (int mt = 0; mt < 2; ++mt) {
                aF[mt].u.x = mask2(xr[mt][h].x, ir[mt][h].x, qq);
                aF[mt].u.y = mask2(xr[mt][h].y, ir[mt][h].y, qq);
                aF[mt].u.z = mask2(xr[mt][h].z, ir[mt][h].z, qq);
                aF[mt].u.w = mask2(xr[mt][h].w, ir[mt][h].w, qq);
            }
#pragma unroll
            for (int mt = 0; mt < 2; ++mt)
#pragma unroll
                for (int nt = 0; nt < 8; ++nt)
                    acc[mt * 8 + nt] = __builtin_amdgcn_mfma_f32_16x16x32_bf16(
                        aF[mt].s8, bF[nt], acc[mt * 8 + nt], 0, 0, 0);
        }
        // scheduling-only barrier: keep the block's 4 waves on the same slab
        // so L1 (32 KB) serves 3 of 4 waves. No data shared -> no waitcnt needed.
        asm volatile("s_barrier" ::: "memory");
    }

    // epilogue: C/D col=lane&15 (o), row=(lane>>4)*4+reg (b); zb==0 adds bias
    int cn = lane & 15, rq = lane >> 4;
    float bv[8];
#pragma unroll
    for (int nt = 0; nt < 8; ++nt)
        bv[nt] = (zb == 0) ? bias[o0 + nt * 16 + cn] : 0.0f;
#pragma unroll
    for (int mt = 0; mt < 2; ++mt)
#pragma unroll
        for (int nt = 0; nt < 8; ++nt) {
            int bb = b0 + wave * 32 + mt * 16 + rq * 4;
            int oo = o0 + nt * 16 + cn;
#pragma unroll
            for (int e = 0; e < 4; ++e)
                atomicAdd(out + (size_t)(bb + e) * OUT_SZ + oo, acc[mt * 8 + nt][e] + bv[nt]);
        }
}

// ---------------- fallback (ws too small): exact fp32 gather ----------------
__global__ void k_naive(const float* __restrict__ x, const int* __restrict__ idx,
                        const float* __restrict__ W, const float* __restrict__ bias,
                        float* __restrict__ out) {
    int b = blockIdx.x;
    int o = threadIdx.x * 4;
    float4 acc = *(const float4*)(bias + o);
    const float* xr = x + (size_t)b * IN_SZ;
    const int*   ir = idx + (size_t)b * IN_SZ;
    for (int i = 0; i < IN_SZ; ++i) {
        float xv = xr[i];
        int q = ir[i];
        float4 w4 = *(const float4*)(W + ((size_t)q * IN_SZ + i) * OUT_SZ + o);
        acc.x += xv * w4.x; acc.y += xv * w4.y;
        acc.z += xv * w4.z; acc.w += xv * w4.w;
    }
    *(float4*)(out + (size_t)b * OUT_SZ + o) = acc;
}

extern "C" void kernel_launch(void* const* d_in, const int* in_sizes, int n_in,
                              void* d_out, int out_size, void* d_ws, size_t ws_size,
                              hipStream_t stream) {
    const float* x    = (const float*)d_in[0];
    const int*   idx  = (const int*)d_in[1];
    const float* W    = (const float*)d_in[2];
    const float* bias = (const float*)d_in[3];
    float* out = (float*)d_out;

    const size_t wf_bytes = (size_t)2048 * 16384;            // 32 MB frag-linear Wt
    if (ws_size < wf_bytes) {
        k_naive<<<dim3(B_SZ), dim3(256), 0, stream>>>(x, idx, W, bias, out);
        return;
    }
    unsigned short* Wf = (unsigned short*)d_ws;

    hipMemsetAsync(d_out, 0, (size_t)out_size * sizeof(float), stream);
    k_build_wf<<<dim3(2048), dim3(256), 0, stream>>>(W, Wf);
    k_gemm<<<dim3(8 * 8 * (B_SZ / 128)), dim3(256), 0, stream>>>(Wf, x, idx, bias, out);
}